// Round 7
// baseline (595.386 us; speedup 1.0000x reference)
//
#include <hip/hip_runtime.h>
#include <hip/hip_bf16.h>
#include <hip/hip_fp8.h>
#include <math.h>

// ---------------------------------------------------------------------------
// PicanetG: Renet (2x BiLSTM, HID=256) + 1x1 conv(484) + softmax + attention.
// Round 6: lstm16 — 16 seqs/WG weight-stationary fp8 recurrence, 100% MFMA
//   M-utilization (4x fewer MFMAs than R5's lstm_fp8). 64 WGs/launch.
//   Epilogue: 4 cells/lane, exp2+rcp (2 trans per nonlinearity).
//   GEMMs (m97-structure LDS-staged), softmax, gather unchanged from R5.
//
// FUSED ws (float units), REQ = 50331648 fl = 201,326,592 B:
//   Gf @ 0         bf16 [32768 n][256 j] ushort4 (64 MiB); later convout fp32
//   Gb @ 16777216  bf16 (64 MiB); later kernT bf16 [8][4096][512] (32 MiB)
//   V  @ 33554432  bf16 [32768][512] (32 MiB); first xt, later Pch
//   HF @ 41943040  bf16 [32768][512] (32 MiB)
// SERIAL ws, REQ = 134,217,728 B: G@0, V@16777216, xt/HF@25165824.
// d_out tail scratch (fl offset): wt bf16 @ +8388608 ([vf;vb;hf;hb][512k]),
//   cw2b @ +9437184, cb2 @ +9568256, wq fp8 @ +9568768.
// ---------------------------------------------------------------------------

typedef __hip_bfloat16 bf16;
typedef short short8 __attribute__((ext_vector_type(8)));
typedef float f4 __attribute__((ext_vector_type(4)));

__device__ __forceinline__ unsigned short bfbits(float f) {
    bf16 h = __float2bfloat16(f);
    return *reinterpret_cast<unsigned short*>(&h);
}
__device__ __forceinline__ float bf2f(unsigned short u) {
    union { unsigned int i; float f; } x; x.i = ((unsigned int)u) << 16; return x.f;
}
__device__ __forceinline__ unsigned char f2fp8(float f) {
    __hip_fp8_e4m3 q(f);
    return *reinterpret_cast<unsigned char*>(&q);
}
// sigmoid/tanh via exp2+rcp (2 trans ops each); graceful at +/-inf.
__device__ __forceinline__ float sigm2(float x) {
    return __builtin_amdgcn_rcpf(1.0f + __builtin_amdgcn_exp2f(x * -1.44269504f));
}
__device__ __forceinline__ float tanh2(float x) {
    return 1.0f - 2.0f * __builtin_amdgcn_rcpf(1.0f + __builtin_amdgcn_exp2f(x * 2.88539008f));
}
__device__ __forceinline__ float sigm(float x) {          // for non-critical paths
    return 1.0f / (1.0f + __expf(-x));
}

// async global->LDS, 16B per lane; lds dest = base + lane*16 (HW rule).
#define GLD16(g, s) __builtin_amdgcn_global_load_lds(                          \
    (const __attribute__((address_space(1))) void*)(g),                        \
    (__attribute__((address_space(3))) void*)(s), 16, 0, 0)

// ---------------------------------------------------------------------------
// prep_weights: wt bf16 [4][1024 g][512 k] ([vf;vb;hf;hb]); cw2b [512][512];
//               cb2 [512]; wq e4m3 [4][1024 g][256 k].
// ---------------------------------------------------------------------------
__global__ __launch_bounds__(256)
void prep_weights(const float* __restrict__ w0, const float* __restrict__ w1,
                  const float* __restrict__ w2, const float* __restrict__ w3,
                  const float* __restrict__ cw, const float* __restrict__ cb,
                  const float* __restrict__ u0, const float* __restrict__ u1,
                  const float* __restrict__ u2, const float* __restrict__ u3,
                  bf16* __restrict__ wt, bf16* __restrict__ cw2b,
                  float* __restrict__ cb2, unsigned char* __restrict__ wq)
{
    int idx = blockIdx.x * 256 + threadIdx.x;
    if (idx < 2097152) {
        int mat = idx >> 19, rem = idx & 524287;
        const float* src = (mat == 0) ? w0 : (mat == 1) ? w1 : (mat == 2) ? w2 : w3;
        wt[idx] = __float2bfloat16(src[rem]);
    } else if (idx < 2097152 + 262144) {
        int r = idx - 2097152; int o = r >> 9, k = r & 511;
        cw2b[r] = __float2bfloat16((o < 484) ? cw[o * 512 + k] : 0.f);
    } else if (idx < 2097152 + 262144 + 512) {
        int o = idx - 2097152 - 262144;
        cb2[o] = (o < 484) ? cb[o] : 0.f;
    } else if (idx < 2097152 + 262144 + 512 + 1048576) {
        int r = idx - 2097152 - 262144 - 512;
        int mat = r >> 18, rem = r & 262143;
        const float* src = (mat == 0) ? u0 : (mat == 1) ? u1 : (mat == 2) ? u2 : u3;
        wq[r] = f2fp8(src[rem]);
    }
}

// ---------------------------------------------------------------------------
// xtrans: x [8][512][64][64] fp32 -> xt [b*4096 + h*64 + w][512 c] bf16.
// ---------------------------------------------------------------------------
__global__ __launch_bounds__(256)
void xtrans(const float* __restrict__ x, bf16* __restrict__ xt)
{
    __shared__ float T[64][65];
    const int tid = threadIdx.x;
    const int bid = blockIdx.x;
    const int b = bid >> 9, h = (bid >> 3) & 63, ct = bid & 7;
    const int c0 = ct << 6;
    const float* xp = x + ((long)(b * 512 + c0) * 64 + h) * 64;
    const int wv = tid >> 6, wl = tid & 63;
    #pragma unroll
    for (int r = 0; r < 16; ++r) {
        int ci = wv + (r << 2);
        T[ci][wl] = xp[(long)ci * 4096 + wl];
    }
    __syncthreads();
    const int wr = tid >> 2, cj = (tid & 3) << 4;
    bf16* op = xt + ((long)(b * 4096 + h * 64 + wr) * 512) + c0 + cj;
    short8 v0, v1;
    #pragma unroll
    for (int i = 0; i < 8; ++i) v0[i] = (short)bfbits(T[cj + i][wr]);
    #pragma unroll
    for (int i = 0; i < 8; ++i) v1[i] = (short)bfbits(T[cj + 8 + i][wr]);
    *(short8*)op = v0;
    *(short8*)(op + 8) = v1;
}

// ---------------------------------------------------------------------------
// gemm_lds: m97-structure MFMA GEMM (R5, unchanged). K=512, BK=64, 128x128.
// ---------------------------------------------------------------------------
template<int MODE>
__global__ __launch_bounds__(256)
void gemm_lds(const bf16* __restrict__ A, const bf16* __restrict__ W,
              const float* __restrict__ biasf, const float* __restrict__ biasb,
              void* __restrict__ outf, void* __restrict__ outb, int dironly)
{
    __shared__ alignas(16) char Abuf[16384];
    __shared__ alignas(16) char Bbuf[16384];
    const int tid = threadIdx.x;
    const int wv = tid >> 6, l = tid & 63;
    const int lm = l & 15, lg = l >> 4;
    const int wm = wv >> 1, wn = wv & 1;

    const int nx = gridDim.x;
    int bid = blockIdx.y * nx + blockIdx.x;
    const int cpx = (nx * gridDim.y) >> 3;
    bid = (bid & 7) * cpx + (bid >> 3);
    const int bx = bid % nx;
    const int n0 = (bid / nx) << 7;

    int dir = 0, jblk = 0, g0 = 0;
    const bf16* Wg = W;
    if (MODE == 0) {
        dir  = (dironly < 0) ? (bx >> 3) : dironly;
        jblk = (dironly < 0) ? (bx & 7) : bx;
    } else {
        g0 = bx << 7;
        if (MODE == 2) Wg += (long)(n0 >> 9) * 2097152;
    }

    f4 acc[4][4];
    #pragma unroll
    for (int mf = 0; mf < 4; ++mf)
        #pragma unroll
        for (int nf = 0; nf < 4; ++nf)
            acc[mf][nf] = (f4){0.f, 0.f, 0.f, 0.f};

    for (int kt = 0; kt < 8; ++kt) {
        const int k0 = kt << 6;
        #pragma unroll
        for (int i = 0; i < 4; ++i) {
            const int seg = (wv << 2) + i;
            const int L = (seg << 10) + l * 16;
            const int row = L >> 7;
            const int off = (L & 127) ^ ((row & 7) << 4);
            const bf16* ga = A + (long)(n0 + row) * 512 + k0 + (off >> 1);
            GLD16(ga, &Abuf[seg << 10]);
        }
        #pragma unroll
        for (int i = 0; i < 4; ++i) {
            const int seg = (wv << 2) + i;
            const int L = (seg << 10) + l * 16;
            const int row = L >> 7;
            const int off = (L & 127) ^ ((row & 7) << 4);
            int wrow;
            if (MODE == 0) wrow = (dir << 10) + ((row >> 5) << 8) + jblk * 32 + (row & 31);
            else           wrow = g0 + row;
            const bf16* gb = Wg + (long)wrow * 512 + k0 + (off >> 1);
            GLD16(gb, &Bbuf[seg << 10]);
        }
        __syncthreads();

        #pragma unroll
        for (int kk = 0; kk < 2; ++kk) {
            short8 af[4], bq[4];
            #pragma unroll
            for (int mf = 0; mf < 4; ++mf) {
                const int row = wm * 64 + mf * 16 + lm;
                const int ad = (row << 7) + ((((kk << 6) + (lg << 4))) ^ ((row & 7) << 4));
                af[mf] = *(const short8*)&Abuf[ad];
            }
            #pragma unroll
            for (int nf = 0; nf < 4; ++nf) {
                const int row = (MODE == 0) ? (nf * 32 + wn * 16 + lm)
                                            : (wn * 64 + nf * 16 + lm);
                const int ad = (row << 7) + ((((kk << 6) + (lg << 4))) ^ ((row & 7) << 4));
                bq[nf] = *(const short8*)&Bbuf[ad];
            }
            #pragma unroll
            for (int mf = 0; mf < 4; ++mf)
                #pragma unroll
                for (int nf = 0; nf < 4; ++nf)
                    acc[mf][nf] = __builtin_amdgcn_mfma_f32_16x16x32_bf16(af[mf], bq[nf], acc[mf][nf], 0, 0, 0);
        }
        __syncthreads();
    }

    if (MODE == 0) {
        const float* bs = dir ? biasb : biasf;
        const int jglob = jblk * 32 + wn * 16 + lm;
        float bv[4];
        #pragma unroll
        for (int nf = 0; nf < 4; ++nf) bv[nf] = bs[nf * 256 + jglob];
        ushort4* Gd = (ushort4*)(dir ? outb : outf);
        #pragma unroll
        for (int mf = 0; mf < 4; ++mf) {
            #pragma unroll
            for (int r = 0; r < 4; ++r) {
                const int n = n0 + wm * 64 + mf * 16 + lg * 4 + r;
                ushort4 u;
                u.x = bfbits(acc[mf][0][r] + bv[0]);
                u.y = bfbits(acc[mf][1][r] + bv[1]);
                u.z = bfbits(acc[mf][2][r] + bv[2]);
                u.w = bfbits(acc[mf][3][r] + bv[3]);
                Gd[(long)n * 256 + jglob] = u;
            }
        }
    } else if (MODE == 1) {
        float bv[4];
        #pragma unroll
        for (int nf = 0; nf < 4; ++nf) bv[nf] = biasf[g0 + wn * 64 + nf * 16 + lm];
        float* o = (float*)outf;
        #pragma unroll
        for (int mf = 0; mf < 4; ++mf)
            #pragma unroll
            for (int r = 0; r < 4; ++r) {
                const int n = n0 + wm * 64 + mf * 16 + lg * 4 + r;
                #pragma unroll
                for (int nf = 0; nf < 4; ++nf)
                    o[(long)n * 512 + g0 + wn * 64 + nf * 16 + lm] = acc[mf][nf][r] + bv[nf];
            }
    } else {
        float* o = (float*)outf;
        #pragma unroll
        for (int mf = 0; mf < 4; ++mf)
            #pragma unroll
            for (int r = 0; r < 4; ++r) {
                const int n = n0 + wm * 64 + mf * 16 + lg * 4 + r;
                #pragma unroll
                for (int nf = 0; nf < 4; ++nf)
                    o[(long)n * 4096 + g0 + wn * 64 + nf * 16 + lm] = acc[mf][nf][r];
            }
    }
}

// ---------------------------------------------------------------------------
// lstm16: weight-stationary fp8 MFMA recurrence, 16 seqs/WG, 16 waves.
// Wave wv owns hidden slice [16wv,16wv+16), 4 gates reg-resident (64 VGPR).
// MFMA M rows = 16 seqs (100% util): A row = seq = lm, k = kt*32+lg*8+j.
// D: seq = lg*4+r, hid col = lm -> lane (lg,lm) runs 4 cells, c in cst[4].
// h in LDS fp8 [2][16 seq][256 col], col rotated by seq*16 (read 2-way free).
// G interleaved ushort4 {i,f,g,o} at [n*256 + j]; 4 rows/lane, prefetch-1
// issued before MFMA block. Out bf16 swapped-on-write (row b*4096+t*64+s).
// Grid: fused 64 WGs (dir = bid>>5), serial 32 WGs + dir_force.
// ---------------------------------------------------------------------------
__global__ __launch_bounds__(1024, 4)
void lstm16(const bf16* __restrict__ Gf, const bf16* __restrict__ Gb,
            const unsigned char* __restrict__ Wqf, const unsigned char* __restrict__ Wqb,
            bf16* __restrict__ Out, int dir_force)
{
    __shared__ unsigned char hbuf[2][16][256];   // 8 KB fp8 h, col-rotated
    const int tid = threadIdx.x;
    const int wv = tid >> 6, l = tid & 63;
    const int lm = l & 15, lg = l >> 4;
    const int j_c = wv * 16 + lm;

    int dir, sblk;
    if (dir_force >= 0) { dir = dir_force; sblk = blockIdx.x; }
    else               { dir = blockIdx.x >> 5; sblk = blockIdx.x & 31; }
    const bf16* G = dir ? Gb : Gf;
    const unsigned char* WQ = dir ? Wqb : Wqf;
    const int s0 = sblk << 4;

    // Whh fp8 B-frags: col g = q*256 + wv*16+lm, k = kt*32 + lg*8 + j
    unsigned long wfrag[4][8];
    #pragma unroll
    for (int q = 0; q < 4; ++q) {
        const unsigned char* wr = WQ + (long)(q * 256 + wv * 16 + lm) * 256 + lg * 8;
        #pragma unroll
        for (int kt = 0; kt < 8; ++kt)
            wfrag[q][kt] = *(const unsigned long*)(wr + kt * 32);
    }

    ((unsigned long*)hbuf)[tid] = 0ul;   // zero both buffers (8192 B)

    float cst[4] = {0.f, 0.f, 0.f, 0.f};

    // G base: lane's 4 seq rows are s0 + lg*4 + r; G4 idx = sg*16384 + t*256 + j_c
    const ushort4* G4 = (const ushort4*)G;
    const long gb0 = (long)(s0 + lg * 4) * 16384 + j_c;
    // Out base: row = (sg>>6)*4096 + t*64 + (sg&63); all 4 r in same 64-block
    const long ob0 = ((long)((s0 >> 6) * 4096 + (s0 & 63) + lg * 4)) * 512 + (dir << 8) + j_c;
    unsigned short* Ou = (unsigned short*)Out;

    ushort4 u[4];
    {
        int t0 = dir ? 63 : 0;
        #pragma unroll
        for (int r = 0; r < 4; ++r) u[r] = G4[gb0 + r * 16384 + t0 * 256];
    }
    __syncthreads();

    for (int step = 0; step < 64; ++step) {
        const int t = dir ? (63 - step) : step;
        const int RB = step & 1, WB = 1 - RB;

        // A-frags: seq row = lm, k = kt*32 + lg*8, col rotated by row*16
        unsigned long af[8];
        {
            const unsigned char* hb = &hbuf[RB][lm][0];
            const int rot = lm << 4;
            #pragma unroll
            for (int kt = 0; kt < 8; ++kt)
                af[kt] = *(const unsigned long*)(hb + (((kt << 5) + (lg << 3) + rot) & 255));
        }

        // acc init from gate pre-activations (consume u)
        f4 ac0, ac1, ac2, ac3;
        #pragma unroll
        for (int r = 0; r < 4; ++r) {
            ac0[r] = bf2f(u[r].x); ac1[r] = bf2f(u[r].y);
            ac2[r] = bf2f(u[r].z); ac3[r] = bf2f(u[r].w);
        }

        // prefetch next step's G early (hides under MFMA block)
        {
            int sp = (step < 63) ? step + 1 : 63;
            int tp = dir ? (63 - sp) : sp;
            #pragma unroll
            for (int r = 0; r < 4; ++r) u[r] = G4[gb0 + r * 16384 + tp * 256];
        }

        // h @ Whh^T : 32 MFMAs, all 16 M-rows useful
        #pragma unroll
        for (int kt = 0; kt < 8; ++kt) {
            ac0 = __builtin_amdgcn_mfma_f32_16x16x32_fp8_fp8((long)af[kt], (long)wfrag[0][kt], ac0, 0, 0, 0);
            ac1 = __builtin_amdgcn_mfma_f32_16x16x32_fp8_fp8((long)af[kt], (long)wfrag[1][kt], ac1, 0, 0, 0);
            ac2 = __builtin_amdgcn_mfma_f32_16x16x32_fp8_fp8((long)af[kt], (long)wfrag[2][kt], ac2, 0, 0, 0);
            ac3 = __builtin_amdgcn_mfma_f32_16x16x32_fp8_fp8((long)af[kt], (long)wfrag[3][kt], ac3, 0, 0, 0);
        }

        // epilogue: 4 cells per lane (seq = lg*4+r, hid = j_c)
        #pragma unroll
        for (int r = 0; r < 4; ++r) {
            float ii = sigm2(ac0[r]);
            float ff = sigm2(ac1[r]);
            float gc = tanh2(ac2[r]);
            float oo = sigm2(ac3[r]);
            float c  = ff * cst[r] + ii * gc;
            cst[r] = c;
            float h_ = oo * tanh2(c);
            const int row = lg * 4 + r;
            hbuf[WB][row][(j_c + (row << 4)) & 255] = f2fp8(h_);
            Ou[ob0 + r * 512 + (long)t * 32768] = bfbits(h_);
        }
        __syncthreads();
    }
}

// ---------------------------------------------------------------------------
// softmax_rows: convout fp32 [32768][512] -> kernT bf16 [32768][512].
// ---------------------------------------------------------------------------
__global__ __launch_bounds__(256)
void softmax_rows(const float* __restrict__ cin, bf16* __restrict__ kout)
{
    const int tid = threadIdx.x;
    const int row = blockIdx.x * 4 + (tid >> 6);
    const int l = tid & 63;
    const float* rp = cin + (long)row * 512 + l * 8;
    float v[8];
    *(float4*)&v[0] = *(const float4*)rp;
    *(float4*)&v[4] = *(const float4*)(rp + 4);
    float m = -3.4e38f;
    #pragma unroll
    for (int i = 0; i < 8; ++i) {
        int o = l * 8 + i;
        if (o < 484) m = fmaxf(m, v[i]);
    }
    #pragma unroll
    for (int d = 1; d < 64; d <<= 1) m = fmaxf(m, __shfl_xor(m, d));
    float e[8], s = 0.f;
    #pragma unroll
    for (int i = 0; i < 8; ++i) {
        int o = l * 8 + i;
        e[i] = (o < 484) ? __expf(v[i] - m) : 0.f;
        s += e[i];
    }
    #pragma unroll
    for (int d = 1; d < 64; d <<= 1) s += __shfl_xor(s, d);
    float inv = 1.f / s;
    short8 st;
    #pragma unroll
    for (int i = 0; i < 8; ++i) st[i] = (short)bfbits(e[i] * inv);
    *(short8*)(kout + (long)row * 512 + l * 8) = st;
}

// ---------------------------------------------------------------------------
// gather_patch: Pch[b*512+c][o] = bf16(x[b, c, 3*(o/22), 3*(o%22)]), 0 o>=484.
// ---------------------------------------------------------------------------
__global__ __launch_bounds__(256)
void gather_patch(const float* __restrict__ x, bf16* __restrict__ Pch)
{
    int idx = blockIdx.x * 256 + threadIdx.x;
    if (idx >= 2097152) return;
    int o = idx & 511, c = (idx >> 9) & 511, b = idx >> 18;
    float v = 0.f;
    if (o < 484) {
        int i = o / 22, jj = o - i * 22;
        v = x[(long)b * 2097152 + (long)c * 4096 + i * 192 + jj * 3];
    }
    Pch[idx] = __float2bfloat16(v);
}

// ---------------------------------------------------------------------------
extern "C" void kernel_launch(void* const* d_in, const int* in_sizes, int n_in,
                              void* d_out, int out_size, void* d_ws, size_t ws_size,
                              hipStream_t stream)
{
    const float* x        = (const float*)d_in[0];
    const float* v_wih_f  = (const float*)d_in[1];
    const float* v_whh_f  = (const float*)d_in[2];
    const float* v_b_f    = (const float*)d_in[3];
    const float* v_wih_b  = (const float*)d_in[4];
    const float* v_whh_b  = (const float*)d_in[5];
    const float* v_b_b    = (const float*)d_in[6];
    const float* h_wih_f  = (const float*)d_in[7];
    const float* h_whh_f  = (const float*)d_in[8];
    const float* h_b_f    = (const float*)d_in[9];
    const float* h_wih_b  = (const float*)d_in[10];
    const float* h_whh_b  = (const float*)d_in[11];
    const float* h_b_b    = (const float*)d_in[12];
    const float* conv_w   = (const float*)d_in[13];
    const float* conv_b   = (const float*)d_in[14];

    const size_t REQ_FUSED  = 50331648UL * 4UL;   // 201,326,592 B
    const size_t REQ_SERIAL = 33554432UL * 4UL;   // 134,217,728 B
    if (ws_size < REQ_SERIAL) return;
    const bool fused = (ws_size >= REQ_FUSED);

    float* wsf = (float*)d_ws;
    float* out = (float*)d_out;

    // d_out tail scratch (dead before final gemm)
    bf16*          wt   = (bf16*)(out + 8388608);
    bf16*          cw2b = (bf16*)(out + 9437184);
    float*         cb2  = out + 9568256;
    unsigned char* wq   = (unsigned char*)(out + 9568768);

    prep_weights<<<13314, 256, 0, stream>>>(v_wih_f, v_wih_b, h_wih_f, h_wih_b,
                                            conv_w, conv_b,
                                            v_whh_f, v_whh_b, h_whh_f, h_whh_b,
                                            wt, cw2b, cb2, wq);
    bf16* wt_v = wt;                 // [vf;vb] 2048 rows
    bf16* wt_h = wt + 1048576;       // [hf;hb] 2048 rows
    unsigned char* wq_vf = wq;
    unsigned char* wq_vb = wq + 262144;
    unsigned char* wq_hf = wq + 524288;
    unsigned char* wq_hb = wq + 786432;

    dim3 gG(16, 256);   // fused gate GEMM: 2 dirs x 8 jblks, 256 row-tiles
    dim3 gGs(8, 256);   // serial gate GEMM: one dir
    dim3 gC(4, 256);    // conv: 512 cols
    dim3 gF(32, 32);    // final: 4096 cols, 4096 rows

    if (fused) {
        bf16*  Gf    = (bf16*)d_ws;
        bf16*  Gb    = (bf16*)(wsf + 16777216);
        bf16*  V     = (bf16*)(wsf + 33554432);
        bf16*  HF    = (bf16*)(wsf + 41943040);
        bf16*  xt    = V;                      // dead after vertical GEMM
        float* convo = (float*)d_ws;           // aliases Gf
        bf16*  kernT = Gb;                     // aliases Gb
        bf16*  Pch   = V;                      // aliases V

        xtrans<<<4096, 256, 0, stream>>>(x, xt);
        gemm_lds<0><<<gG, 256, 0, stream>>>(xt, wt_v, v_b_f, v_b_b, Gf, Gb, -1);
        lstm16<<<64, 1024, 0, stream>>>(Gf, Gb, wq_vf, wq_vb, V, -1);

        gemm_lds<0><<<gG, 256, 0, stream>>>(V, wt_h, h_b_f, h_b_b, Gf, Gb, -1);
        lstm16<<<64, 1024, 0, stream>>>(Gf, Gb, wq_hf, wq_hb, HF, -1);

        gemm_lds<1><<<gC, 256, 0, stream>>>(HF, cw2b, cb2, nullptr, convo, nullptr, 0);
        softmax_rows<<<8192, 256, 0, stream>>>(convo, kernT);
        gather_patch<<<8192, 256, 0, stream>>>(x, Pch);
        gemm_lds<2><<<gF, 256, 0, stream>>>(Pch, kernT, nullptr, nullptr, out, nullptr, 0);
    } else {
        bf16*  G     = (bf16*)d_ws;
        bf16*  V     = (bf16*)(wsf + 16777216);
        bf16*  xt    = (bf16*)(wsf + 25165824);
        bf16*  HF    = xt;
        float* convo = (float*)d_ws;           // aliases G
        bf16*  kernT = V;
        bf16*  Pch   = (bf16*)d_ws;            // aliases convo after softmax

        xtrans<<<4096, 256, 0, stream>>>(x, xt);
        gemm_lds<0><<<gGs, 256, 0, stream>>>(xt, wt_v, v_b_f, v_b_b, G, G, 0);
        lstm16<<<32, 1024, 0, stream>>>(G, G, wq_vf, wq_vf, V, 0);
        gemm_lds<0><<<gGs, 256, 0, stream>>>(xt, wt_v, v_b_f, v_b_b, G, G, 1);
        lstm16<<<32, 1024, 0, stream>>>(G, G, wq_vb, wq_vb, V, 1);

        gemm_lds<0><<<gGs, 256, 0, stream>>>(V, wt_h, h_b_f, h_b_b, G, G, 0);
        lstm16<<<32, 1024, 0, stream>>>(G, G, wq_hf, wq_hf, HF, 0);
        gemm_lds<0><<<gGs, 256, 0, stream>>>(V, wt_h, h_b_f, h_b_b, G, G, 1);
        lstm16<<<32, 1024, 0, stream>>>(G, G, wq_hb, wq_hb, HF, 1);

        gemm_lds<1><<<gC, 256, 0, stream>>>(HF, cw2b, cb2, nullptr, convo, nullptr, 0);
        softmax_rows<<<8192, 256, 0, stream>>>(convo, kernT);
        gather_patch<<<8192, 256, 0, stream>>>(x, Pch);
        gemm_lds<2><<<gF, 256, 0, stream>>>(Pch, kernT, nullptr, nullptr, out, nullptr, 0);
    }
}

// Round 8
// 489.815 us; speedup vs baseline: 1.2155x; 1.2155x over previous
//
#include <hip/hip_runtime.h>
#include <hip/hip_bf16.h>
#include <hip/hip_fp8.h>
#include <math.h>

// ---------------------------------------------------------------------------
// PicanetG: Renet (2x BiLSTM, HID=256) + 1x1 conv(484) + softmax + attention.
// Round 7: lstm4s — spread-row fp8 recurrence. 4 seqs/WG at MFMA rows
//   {0,4,8,12} -> each lane owns ONE cell (seq=lg, hid=wv*16+lm). 256 WGs
//   (fused) = 1 WG/CU (VGPR ~110 forces 16 waves/CU max -> no 2-WG packing,
//   the R6 bug: VGPR=64 allowed 2 WGs/CU -> 32 CUs -> G-read BW-starved).
//   2-step G prefetch. GEMMs / softmax / gather unchanged from R6.
//
// FUSED ws (float units), REQ = 50331648 fl = 201,326,592 B:
//   Gf @ 0         bf16 [32768 n][256 j] ushort4 (64 MiB); later convout fp32
//   Gb @ 16777216  bf16 (64 MiB); later kernT bf16 [8][4096][512] (32 MiB)
//   V  @ 33554432  bf16 [32768][512] (32 MiB); first xt, later Pch
//   HF @ 41943040  bf16 [32768][512] (32 MiB)
// SERIAL ws, REQ = 134,217,728 B: G@0, V@16777216, xt/HF@25165824.
// d_out tail scratch (fl offset): wt bf16 @ +8388608 ([vf;vb;hf;hb][512k]),
//   cw2b @ +9437184, cb2 @ +9568256, wq fp8 @ +9568768.
// ---------------------------------------------------------------------------

typedef __hip_bfloat16 bf16;
typedef short short8 __attribute__((ext_vector_type(8)));
typedef float f4 __attribute__((ext_vector_type(4)));

__device__ __forceinline__ unsigned short bfbits(float f) {
    bf16 h = __float2bfloat16(f);
    return *reinterpret_cast<unsigned short*>(&h);
}
__device__ __forceinline__ float bf2f(unsigned short u) {
    union { unsigned int i; float f; } x; x.i = ((unsigned int)u) << 16; return x.f;
}
__device__ __forceinline__ unsigned char f2fp8(float f) {
    __hip_fp8_e4m3 q(f);
    return *reinterpret_cast<unsigned char*>(&q);
}
// sigmoid/tanh via exp2+rcp (2 trans ops each); graceful at +/-inf.
__device__ __forceinline__ float sigm2(float x) {
    return __builtin_amdgcn_rcpf(1.0f + __builtin_amdgcn_exp2f(x * -1.44269504f));
}
__device__ __forceinline__ float tanh2(float x) {
    return 1.0f - 2.0f * __builtin_amdgcn_rcpf(1.0f + __builtin_amdgcn_exp2f(x * 2.88539008f));
}

// async global->LDS, 16B per lane; lds dest = base + lane*16 (HW rule).
#define GLD16(g, s) __builtin_amdgcn_global_load_lds(                          \
    (const __attribute__((address_space(1))) void*)(g),                        \
    (__attribute__((address_space(3))) void*)(s), 16, 0, 0)

// ---------------------------------------------------------------------------
// prep_weights: wt bf16 [4][1024 g][512 k] ([vf;vb;hf;hb]); cw2b [512][512];
//               cb2 [512]; wq e4m3 [4][1024 g][256 k].
// ---------------------------------------------------------------------------
__global__ __launch_bounds__(256)
void prep_weights(const float* __restrict__ w0, const float* __restrict__ w1,
                  const float* __restrict__ w2, const float* __restrict__ w3,
                  const float* __restrict__ cw, const float* __restrict__ cb,
                  const float* __restrict__ u0, const float* __restrict__ u1,
                  const float* __restrict__ u2, const float* __restrict__ u3,
                  bf16* __restrict__ wt, bf16* __restrict__ cw2b,
                  float* __restrict__ cb2, unsigned char* __restrict__ wq)
{
    int idx = blockIdx.x * 256 + threadIdx.x;
    if (idx < 2097152) {
        int mat = idx >> 19, rem = idx & 524287;
        const float* src = (mat == 0) ? w0 : (mat == 1) ? w1 : (mat == 2) ? w2 : w3;
        wt[idx] = __float2bfloat16(src[rem]);
    } else if (idx < 2097152 + 262144) {
        int r = idx - 2097152; int o = r >> 9, k = r & 511;
        cw2b[r] = __float2bfloat16((o < 484) ? cw[o * 512 + k] : 0.f);
    } else if (idx < 2097152 + 262144 + 512) {
        int o = idx - 2097152 - 262144;
        cb2[o] = (o < 484) ? cb[o] : 0.f;
    } else if (idx < 2097152 + 262144 + 512 + 1048576) {
        int r = idx - 2097152 - 262144 - 512;
        int mat = r >> 18, rem = r & 262143;
        const float* src = (mat == 0) ? u0 : (mat == 1) ? u1 : (mat == 2) ? u2 : u3;
        wq[r] = f2fp8(src[rem]);
    }
}

// ---------------------------------------------------------------------------
// xtrans: x [8][512][64][64] fp32 -> xt [b*4096 + h*64 + w][512 c] bf16.
// ---------------------------------------------------------------------------
__global__ __launch_bounds__(256)
void xtrans(const float* __restrict__ x, bf16* __restrict__ xt)
{
    __shared__ float T[64][65];
    const int tid = threadIdx.x;
    const int bid = blockIdx.x;
    const int b = bid >> 9, h = (bid >> 3) & 63, ct = bid & 7;
    const int c0 = ct << 6;
    const float* xp = x + ((long)(b * 512 + c0) * 64 + h) * 64;
    const int wv = tid >> 6, wl = tid & 63;
    #pragma unroll
    for (int r = 0; r < 16; ++r) {
        int ci = wv + (r << 2);
        T[ci][wl] = xp[(long)ci * 4096 + wl];
    }
    __syncthreads();
    const int wr = tid >> 2, cj = (tid & 3) << 4;
    bf16* op = xt + ((long)(b * 4096 + h * 64 + wr) * 512) + c0 + cj;
    short8 v0, v1;
    #pragma unroll
    for (int i = 0; i < 8; ++i) v0[i] = (short)bfbits(T[cj + i][wr]);
    #pragma unroll
    for (int i = 0; i < 8; ++i) v1[i] = (short)bfbits(T[cj + 8 + i][wr]);
    *(short8*)op = v0;
    *(short8*)(op + 8) = v1;
}

// ---------------------------------------------------------------------------
// gemm_lds: m97-structure MFMA GEMM (unchanged). K=512, BK=64, 128x128.
// ---------------------------------------------------------------------------
template<int MODE>
__global__ __launch_bounds__(256)
void gemm_lds(const bf16* __restrict__ A, const bf16* __restrict__ W,
              const float* __restrict__ biasf, const float* __restrict__ biasb,
              void* __restrict__ outf, void* __restrict__ outb, int dironly)
{
    __shared__ alignas(16) char Abuf[16384];
    __shared__ alignas(16) char Bbuf[16384];
    const int tid = threadIdx.x;
    const int wv = tid >> 6, l = tid & 63;
    const int lm = l & 15, lg = l >> 4;
    const int wm = wv >> 1, wn = wv & 1;

    const int nx = gridDim.x;
    int bid = blockIdx.y * nx + blockIdx.x;
    const int cpx = (nx * gridDim.y) >> 3;
    bid = (bid & 7) * cpx + (bid >> 3);
    const int bx = bid % nx;
    const int n0 = (bid / nx) << 7;

    int dir = 0, jblk = 0, g0 = 0;
    const bf16* Wg = W;
    if (MODE == 0) {
        dir  = (dironly < 0) ? (bx >> 3) : dironly;
        jblk = (dironly < 0) ? (bx & 7) : bx;
    } else {
        g0 = bx << 7;
        if (MODE == 2) Wg += (long)(n0 >> 9) * 2097152;
    }

    f4 acc[4][4];
    #pragma unroll
    for (int mf = 0; mf < 4; ++mf)
        #pragma unroll
        for (int nf = 0; nf < 4; ++nf)
            acc[mf][nf] = (f4){0.f, 0.f, 0.f, 0.f};

    for (int kt = 0; kt < 8; ++kt) {
        const int k0 = kt << 6;
        #pragma unroll
        for (int i = 0; i < 4; ++i) {
            const int seg = (wv << 2) + i;
            const int L = (seg << 10) + l * 16;
            const int row = L >> 7;
            const int off = (L & 127) ^ ((row & 7) << 4);
            const bf16* ga = A + (long)(n0 + row) * 512 + k0 + (off >> 1);
            GLD16(ga, &Abuf[seg << 10]);
        }
        #pragma unroll
        for (int i = 0; i < 4; ++i) {
            const int seg = (wv << 2) + i;
            const int L = (seg << 10) + l * 16;
            const int row = L >> 7;
            const int off = (L & 127) ^ ((row & 7) << 4);
            int wrow;
            if (MODE == 0) wrow = (dir << 10) + ((row >> 5) << 8) + jblk * 32 + (row & 31);
            else           wrow = g0 + row;
            const bf16* gb = Wg + (long)wrow * 512 + k0 + (off >> 1);
            GLD16(gb, &Bbuf[seg << 10]);
        }
        __syncthreads();

        #pragma unroll
        for (int kk = 0; kk < 2; ++kk) {
            short8 af[4], bq[4];
            #pragma unroll
            for (int mf = 0; mf < 4; ++mf) {
                const int row = wm * 64 + mf * 16 + lm;
                const int ad = (row << 7) + ((((kk << 6) + (lg << 4))) ^ ((row & 7) << 4));
                af[mf] = *(const short8*)&Abuf[ad];
            }
            #pragma unroll
            for (int nf = 0; nf < 4; ++nf) {
                const int row = (MODE == 0) ? (nf * 32 + wn * 16 + lm)
                                            : (wn * 64 + nf * 16 + lm);
                const int ad = (row << 7) + ((((kk << 6) + (lg << 4))) ^ ((row & 7) << 4));
                bq[nf] = *(const short8*)&Bbuf[ad];
            }
            #pragma unroll
            for (int mf = 0; mf < 4; ++mf)
                #pragma unroll
                for (int nf = 0; nf < 4; ++nf)
                    acc[mf][nf] = __builtin_amdgcn_mfma_f32_16x16x32_bf16(af[mf], bq[nf], acc[mf][nf], 0, 0, 0);
        }
        __syncthreads();
    }

    if (MODE == 0) {
        const float* bs = dir ? biasb : biasf;
        const int jglob = jblk * 32 + wn * 16 + lm;
        float bv[4];
        #pragma unroll
        for (int nf = 0; nf < 4; ++nf) bv[nf] = bs[nf * 256 + jglob];
        ushort4* Gd = (ushort4*)(dir ? outb : outf);
        #pragma unroll
        for (int mf = 0; mf < 4; ++mf) {
            #pragma unroll
            for (int r = 0; r < 4; ++r) {
                const int n = n0 + wm * 64 + mf * 16 + lg * 4 + r;
                ushort4 u;
                u.x = bfbits(acc[mf][0][r] + bv[0]);
                u.y = bfbits(acc[mf][1][r] + bv[1]);
                u.z = bfbits(acc[mf][2][r] + bv[2]);
                u.w = bfbits(acc[mf][3][r] + bv[3]);
                Gd[(long)n * 256 + jglob] = u;
            }
        }
    } else if (MODE == 1) {
        float bv[4];
        #pragma unroll
        for (int nf = 0; nf < 4; ++nf) bv[nf] = biasf[g0 + wn * 64 + nf * 16 + lm];
        float* o = (float*)outf;
        #pragma unroll
        for (int mf = 0; mf < 4; ++mf)
            #pragma unroll
            for (int r = 0; r < 4; ++r) {
                const int n = n0 + wm * 64 + mf * 16 + lg * 4 + r;
                #pragma unroll
                for (int nf = 0; nf < 4; ++nf)
                    o[(long)n * 512 + g0 + wn * 64 + nf * 16 + lm] = acc[mf][nf][r] + bv[nf];
            }
    } else {
        float* o = (float*)outf;
        #pragma unroll
        for (int mf = 0; mf < 4; ++mf)
            #pragma unroll
            for (int r = 0; r < 4; ++r) {
                const int n = n0 + wm * 64 + mf * 16 + lg * 4 + r;
                #pragma unroll
                for (int nf = 0; nf < 4; ++nf)
                    o[(long)n * 4096 + g0 + wn * 64 + nf * 16 + lm] = acc[mf][nf][r];
            }
    }
}

// ---------------------------------------------------------------------------
// lstm4s: spread-row fp8 MFMA recurrence, 4 seqs/WG, 16 waves, 1 WG/CU.
// Seq s sits at MFMA A/D row 4s -> D row 4s = lane lg=s, reg 0. Each lane
// owns ONE cell: seq = lg, hid = wv*16+lm. A rows lm&3!=0 are constant zero.
// wfrag fp8 64 VGPR + af 16 + acc 16 + misc ~= 110 VGPR: >64 so only 16
// waves/CU fit (exactly one WG) -> full-chip G-read BW with 256 WGs.
// h in LDS fp8 [2][4 seq][256], col rotated by seq*16. G interleaved ushort4
// {i,f,g,o} at [n*256+j]; one load/lane/step, 2-step-deep prefetch (uA/uB).
// Out bf16 swapped-on-write: row = (sg>>6)*4096 + t*64 + (sg&63).
// Grid: fused 256 WGs (dir = bid>>7), serial 128 WGs + dir_force.
// ---------------------------------------------------------------------------
__global__ __launch_bounds__(1024, 4)
void lstm4s(const bf16* __restrict__ Gf, const bf16* __restrict__ Gb,
            const unsigned char* __restrict__ Wqf, const unsigned char* __restrict__ Wqb,
            bf16* __restrict__ Out, int dir_force)
{
    __shared__ unsigned char hbuf[2][4][256];   // 2 KB fp8 h, col-rotated
    const int tid = threadIdx.x;
    const int wv = tid >> 6, l = tid & 63;
    const int lm = l & 15, lg = l >> 4;
    const int j_c = wv * 16 + lm;
    const bool arow = ((lm & 3) == 0);          // lanes supplying nonzero A rows
    const int s_a = lm >> 2;                    // that row's seq

    int dir, sblk;
    if (dir_force >= 0) { dir = dir_force; sblk = blockIdx.x; }
    else               { dir = blockIdx.x >> 7; sblk = blockIdx.x & 127; }
    const bf16* G = dir ? Gb : Gf;
    const unsigned char* WQ = dir ? Wqb : Wqf;
    const int s0 = sblk << 2;

    // Whh fp8 B-frags: col g = q*256 + wv*16+lm, k = kt*32 + lg*8 + j
    unsigned long wfrag[4][8];
    #pragma unroll
    for (int q = 0; q < 4; ++q) {
        const unsigned char* wr = WQ + (long)(q * 256 + wv * 16 + lm) * 256 + lg * 8;
        #pragma unroll
        for (int kt = 0; kt < 8; ++kt)
            wfrag[q][kt] = *(const unsigned long*)(wr + kt * 32);
    }

    if (tid < 256) ((unsigned long*)hbuf)[tid] = 0ul;   // zero both buffers (2 KB)

    float cst = 0.f;                            // ONE cell per lane
    const ushort4* G4 = (const ushort4*)G;
    const int sg = s0 + lg;                     // this lane's seq
    const long gb0 = (long)sg * 16384 + j_c;
    const long ob0 = ((long)((s0 >> 6) * 4096 + (s0 & 63) + lg)) * 512 + (dir << 8) + j_c;
    unsigned short* Ou = (unsigned short*)Out;

    ushort4 uA, uB;
    {
        int t0 = dir ? 63 : 0, t1 = dir ? 62 : 1;
        uA = G4[gb0 + (long)t0 * 256];
        uB = G4[gb0 + (long)t1 * 256];
    }
    __syncthreads();

#define LSTM_STEP(SP, UREG, RB, WB)                                             \
    {                                                                           \
        const int t_ = dir ? (63 - (SP)) : (SP);                                \
        /* A-frags: row lm; rows lm&3!=0 are zero; row 4s reads h[s] */         \
        unsigned long af[8];                                                    \
        _Pragma("unroll")                                                       \
        for (int kt = 0; kt < 8; ++kt) af[kt] = 0ul;                            \
        if (arow) {                                                             \
            const unsigned char* hb = &hbuf[RB][s_a][0];                        \
            const int rot = s_a << 4;                                           \
            _Pragma("unroll")                                                   \
            for (int kt = 0; kt < 8; ++kt)                                      \
                af[kt] = *(const unsigned long*)(hb + (((kt << 5) + (lg << 3) + rot) & 255)); \
        }                                                                       \
        /* C init: row 4s (this lane reg 0) = G pre-acts; others 0 */           \
        f4 ac0 = {0.f,0.f,0.f,0.f}, ac1 = {0.f,0.f,0.f,0.f};                    \
        f4 ac2 = {0.f,0.f,0.f,0.f}, ac3 = {0.f,0.f,0.f,0.f};                    \
        ac0[0] = bf2f(UREG.x); ac1[0] = bf2f(UREG.y);                           \
        ac2[0] = bf2f(UREG.z); ac3[0] = bf2f(UREG.w);                           \
        /* prefetch G for step SP+2 (2-deep) */                                 \
        {                                                                       \
            int sp2 = (SP) + 2; if (sp2 > 63) sp2 = 63;                         \
            int tp = dir ? (63 - sp2) : sp2;                                    \
            UREG = G4[gb0 + (long)tp * 256];                                    \
        }                                                                       \
        _Pragma("unroll")                                                       \
        for (int kt = 0; kt < 8; ++kt) {                                        \
            ac0 = __builtin_amdgcn_mfma_f32_16x16x32_fp8_fp8((long)af[kt], (long)wfrag[0][kt], ac0, 0, 0, 0); \
            ac1 = __builtin_amdgcn_mfma_f32_16x16x32_fp8_fp8((long)af[kt], (long)wfrag[1][kt], ac1, 0, 0, 0); \
            ac2 = __builtin_amdgcn_mfma_f32_16x16x32_fp8_fp8((long)af[kt], (long)wfrag[2][kt], ac2, 0, 0, 0); \
            ac3 = __builtin_amdgcn_mfma_f32_16x16x32_fp8_fp8((long)af[kt], (long)wfrag[3][kt], ac3, 0, 0, 0); \
        }                                                                       \
        /* cell: this lane's (seq=lg, hid=j_c) in reg 0 of each gate */         \
        {                                                                       \
            float ii = sigm2(ac0[0]);                                           \
            float ff = sigm2(ac1[0]);                                           \
            float gc = tanh2(ac2[0]);                                           \
            float oo = sigm2(ac3[0]);                                           \
            float c  = ff * cst + ii * gc;                                      \
            cst = c;                                                            \
            float h_ = oo * tanh2(c);                                           \
            hbuf[WB][lg][((j_c) + (lg << 4)) & 255] = f2fp8(h_);                \
            Ou[ob0 + (long)t_ * 32768] = bfbits(h_);                            \
        }                                                                       \
        __syncthreads();                                                        \
    }

    for (int sp = 0; sp < 64; sp += 2) {
        LSTM_STEP(sp,     uA, 0, 1)
        LSTM_STEP(sp + 1, uB, 1, 0)
    }
#undef LSTM_STEP
}

// ---------------------------------------------------------------------------
// softmax_rows: convout fp32 [32768][512] -> kernT bf16 [32768][512].
// ---------------------------------------------------------------------------
__global__ __launch_bounds__(256)
void softmax_rows(const float* __restrict__ cin, bf16* __restrict__ kout)
{
    const int tid = threadIdx.x;
    const int row = blockIdx.x * 4 + (tid >> 6);
    const int l = tid & 63;
    const float* rp = cin + (long)row * 512 + l * 8;
    float v[8];
    *(float4*)&v[0] = *(const float4*)rp;
    *(float4*)&v[4] = *(const float4*)(rp + 4);
    float m = -3.4e38f;
    #pragma unroll
    for (int i = 0; i < 8; ++i) {
        int o = l * 8 + i;
        if (o < 484) m = fmaxf(m, v[i]);
    }
    #pragma unroll
    for (int d = 1; d < 64; d <<= 1) m = fmaxf(m, __shfl_xor(m, d));
    float e[8], s = 0.f;
    #pragma unroll
    for (int i = 0; i < 8; ++i) {
        int o = l * 8 + i;
        e[i] = (o < 484) ? __expf(v[i] - m) : 0.f;
        s += e[i];
    }
    #pragma unroll
    for (int d = 1; d < 64; d <<= 1) s += __shfl_xor(s, d);
    float inv = 1.f / s;
    short8 st;
    #pragma unroll
    for (int i = 0; i < 8; ++i) st[i] = (short)bfbits(e[i] * inv);
    *(short8*)(kout + (long)row * 512 + l * 8) = st;
}

// ---------------------------------------------------------------------------
// gather_patch: Pch[b*512+c][o] = bf16(x[b, c, 3*(o/22), 3*(o%22)]), 0 o>=484.
// ---------------------------------------------------------------------------
__global__ __launch_bounds__(256)
void gather_patch(const float* __restrict__ x, bf16* __restrict__ Pch)
{
    int idx = blockIdx.x * 256 + threadIdx.x;
    if (idx >= 2097152) return;
    int o = idx & 511, c = (idx >> 9) & 511, b = idx >> 18;
    float v = 0.f;
    if (o < 484) {
        int i = o / 22, jj = o - i * 22;
        v = x[(long)b * 2097152 + (long)c * 4096 + i * 192 + jj * 3];
    }
    Pch[idx] = __float2bfloat16(v);
}

// ---------------------------------------------------------------------------
extern "C" void kernel_launch(void* const* d_in, const int* in_sizes, int n_in,
                              void* d_out, int out_size, void* d_ws, size_t ws_size,
                              hipStream_t stream)
{
    const float* x        = (const float*)d_in[0];
    const float* v_wih_f  = (const float*)d_in[1];
    const float* v_whh_f  = (const float*)d_in[2];
    const float* v_b_f    = (const float*)d_in[3];
    const float* v_wih_b  = (const float*)d_in[4];
    const float* v_whh_b  = (const float*)d_in[5];
    const float* v_b_b    = (const float*)d_in[6];
    const float* h_wih_f  = (const float*)d_in[7];
    const float* h_whh_f  = (const float*)d_in[8];
    const float* h_b_f    = (const float*)d_in[9];
    const float* h_wih_b  = (const float*)d_in[10];
    const float* h_whh_b  = (const float*)d_in[11];
    const float* h_b_b    = (const float*)d_in[12];
    const float* conv_w   = (const float*)d_in[13];
    const float* conv_b   = (const float*)d_in[14];

    const size_t REQ_FUSED  = 50331648UL * 4UL;   // 201,326,592 B
    const size_t REQ_SERIAL = 33554432UL * 4UL;   // 134,217,728 B
    if (ws_size < REQ_SERIAL) return;
    const bool fused = (ws_size >= REQ_FUSED);

    float* wsf = (float*)d_ws;
    float* out = (float*)d_out;

    // d_out tail scratch (dead before final gemm)
    bf16*          wt   = (bf16*)(out + 8388608);
    bf16*          cw2b = (bf16*)(out + 9437184);
    float*         cb2  = out + 9568256;
    unsigned char* wq   = (unsigned char*)(out + 9568768);

    prep_weights<<<13314, 256, 0, stream>>>(v_wih_f, v_wih_b, h_wih_f, h_wih_b,
                                            conv_w, conv_b,
                                            v_whh_f, v_whh_b, h_whh_f, h_whh_b,
                                            wt, cw2b, cb2, wq);
    bf16* wt_v = wt;                 // [vf;vb] 2048 rows
    bf16* wt_h = wt + 1048576;       // [hf;hb] 2048 rows
    unsigned char* wq_vf = wq;
    unsigned char* wq_vb = wq + 262144;
    unsigned char* wq_hf = wq + 524288;
    unsigned char* wq_hb = wq + 786432;

    dim3 gG(16, 256);   // fused gate GEMM: 2 dirs x 8 jblks, 256 row-tiles
    dim3 gGs(8, 256);   // serial gate GEMM: one dir
    dim3 gC(4, 256);    // conv: 512 cols
    dim3 gF(32, 32);    // final: 4096 cols, 4096 rows

    if (fused) {
        bf16*  Gf    = (bf16*)d_ws;
        bf16*  Gb    = (bf16*)(wsf + 16777216);
        bf16*  V     = (bf16*)(wsf + 33554432);
        bf16*  HF    = (bf16*)(wsf + 41943040);
        bf16*  xt    = V;                      // dead after vertical GEMM
        float* convo = (float*)d_ws;           // aliases Gf
        bf16*  kernT = Gb;                     // aliases Gb
        bf16*  Pch   = V;                      // aliases V

        xtrans<<<4096, 256, 0, stream>>>(x, xt);
        gemm_lds<0><<<gG, 256, 0, stream>>>(xt, wt_v, v_b_f, v_b_b, Gf, Gb, -1);
        lstm4s<<<256, 1024, 0, stream>>>(Gf, Gb, wq_vf, wq_vb, V, -1);

        gemm_lds<0><<<gG, 256, 0, stream>>>(V, wt_h, h_b_f, h_b_b, Gf, Gb, -1);
        lstm4s<<<256, 1024, 0, stream>>>(Gf, Gb, wq_hf, wq_hb, HF, -1);

        gemm_lds<1><<<gC, 256, 0, stream>>>(HF, cw2b, cb2, nullptr, convo, nullptr, 0);
        softmax_rows<<<8192, 256, 0, stream>>>(convo, kernT);
        gather_patch<<<8192, 256, 0, stream>>>(x, Pch);
        gemm_lds<2><<<gF, 256, 0, stream>>>(Pch, kernT, nullptr, nullptr, out, nullptr, 0);
    } else {
        bf16*  G     = (bf16*)d_ws;
        bf16*  V     = (bf16*)(wsf + 16777216);
        bf16*  xt    = (bf16*)(wsf + 25165824);
        bf16*  HF    = xt;
        float* convo = (float*)d_ws;           // aliases G
        bf16*  kernT = V;
        bf16*  Pch   = (bf16*)d_ws;            // aliases convo after softmax

        xtrans<<<4096, 256, 0, stream>>>(x, xt);
        gemm_lds<0><<<gGs, 256, 0, stream>>>(xt, wt_v, v_b_f, v_b_b, G, G, 0);
        lstm4s<<<128, 1024, 0, stream>>>(G, G, wq_vf, wq_vf, V, 0);
        gemm_lds<0><<<gGs, 256, 0, stream>>>(xt, wt_v, v_b_f, v_b_b, G, G, 1);
        lstm4s<<<128, 1024, 0, stream>>>(G, G, wq_vb, wq_vb, V, 1);

        gemm_lds<0><<<gGs, 256, 0, stream>>>(V, wt_h, h_b_f, h_b_b, G, G, 0);
        lstm4s<<<128, 1024, 0, stream>>>(G, G, wq_hf, wq_hf, HF, 0);
        gemm_lds<0><<<gGs, 256, 0, stream>>>(V, wt_h, h_b_f, h_b_b, G, G, 1);
        lstm4s<<<128, 1024, 0, stream>>>(G, G, wq_hb, wq_hb, HF, 1);

        gemm_lds<1><<<gC, 256, 0, stream>>>(HF, cw2b, cb2, nullptr, convo, nullptr, 0);
        softmax_rows<<<8192, 256, 0, stream>>>(convo, kernT);
        gather_patch<<<8192, 256, 0, stream>>>(x, Pch);
        gemm_lds<2><<<gF, 256, 0, stream>>>(Pch, kernT, nullptr, nullptr, out, nullptr, 0);
    }
}